// Round 5
// baseline (148.120 us; speedup 1.0000x reference)
//
#include <hip/hip_runtime.h>

#define NTYPES 11
#define BLOCK  256
#define ITEMS  8
#define CHUNK  (BLOCK * ITEMS)   // 2048 atoms per block
#define PERMAX 32                // per-lane scan elements (B <= 2048)

// ---------------------------------------------------------------------------
// Kernel 1: per-block per-type histogram.
// bc[t*B + b] = number of atoms of type t in block b's chunk.
// ---------------------------------------------------------------------------
__global__ __launch_bounds__(BLOCK) void hist_kernel(
    const int* __restrict__ types, int N, int B, int* __restrict__ bc) {
  __shared__ int shCnt[NTYPES];
  const int tid = threadIdx.x;
  const int b = blockIdx.x;
  if (tid < NTYPES) shCnt[tid] = 0;
  __syncthreads();

  const int run = b * CHUNK + tid * ITEMS;
  int cnt[NTYPES];
#pragma unroll
  for (int t = 0; t < NTYPES; ++t) cnt[t] = 0;

  if (run < N) {
    const int4* p = (const int4*)(types + run);
    int4 a0 = p[0], a1 = p[1];
    int ty[ITEMS] = {a0.x, a0.y, a0.z, a0.w, a1.x, a1.y, a1.z, a1.w};
#pragma unroll
    for (int k = 0; k < ITEMS; ++k) {
#pragma unroll
      for (int t = 0; t < NTYPES; ++t) cnt[t] += (ty[k] == t) ? 1 : 0;
    }
  }

  const int lane = tid & 63;
#pragma unroll
  for (int t = 0; t < NTYPES; ++t) {
    int v = cnt[t];
    for (int o = 32; o >= 1; o >>= 1) v += __shfl_down(v, o);
    if (lane == 0) atomicAdd(&shCnt[t], v);
  }
  __syncthreads();
  if (tid < NTYPES) bc[tid * B + b] = shCnt[tid];
}

// ---------------------------------------------------------------------------
// Kernel 2: one block, 11 waves; wave t scans type t's block-counts.
// Lane-serial decomposition: lane l owns counts [l*per, l*per+per). One
// 6-stage shfl scan of the per-lane sums; direct writeback (~21.5K dwords).
// ---------------------------------------------------------------------------
__global__ __launch_bounds__(NTYPES * 64) void scan_kernel(
    const int* __restrict__ bc, int B, int* __restrict__ scanOut,
    int* __restrict__ offs, float* __restrict__ outTail) {
  __shared__ int totals[NTYPES];
  const int lane = threadIdx.x & 63;
  const int t = threadIdx.x >> 6;
  const int per = (B + 63) >> 6;  // 31 for B=1954
  const int base = lane * per;

  int x[PERMAX];
#pragma unroll
  for (int j = 0; j < PERMAX; ++j) {
    const int idx = base + j;
    x[j] = (j < per && idx < B) ? bc[t * B + idx] : 0;
  }
  int s = 0;
#pragma unroll
  for (int j = 0; j < PERMAX; ++j) s += x[j];

  int incl = s;
#pragma unroll
  for (int o = 1; o < 64; o <<= 1) {
    int v = __shfl_up(incl, o);
    if (lane >= o) incl += v;
  }
  int run = incl - s;  // exclusive prefix of this lane's first element
  const int total = __shfl(incl, 63);

#pragma unroll
  for (int j = 0; j < PERMAX; ++j) {
    const int idx = base + j;
    if (j < per && idx < B) scanOut[t * B + idx] = run;
    run += x[j];
  }
  if (lane == 0) totals[t] = total;
  __syncthreads();

  if (threadIdx.x == 0) {
    int off = 0;
    for (int u = 0; u < NTYPES; ++u) {
      const int c = totals[u];
      offs[u] = off;
      outTail[u] = (float)c;            // counts (as float values)
      outTail[NTYPES + u] = (float)off; // offsets (as float values)
      off += c;
    }
  }
}

// ---------------------------------------------------------------------------
// Kernel 3: stable DIRECT scatter (no LDS staging, no copy-out).
// Stability makes each type's output globally contiguous and written in
// near-lane-order, so L2 write-combining assembles full lines; every out
// line is fully written exactly once (only ~NTYPES segment-boundary lines
// are partial). Removes: 24 KB LDS round-trip, 3 of 4 barriers, ~300 VALU
// of copy-out segment-search per thread. LDS -> ~220 B, occupancy cap gone.
// rank[t] registers hold the GLOBAL slot for type t directly.
// ---------------------------------------------------------------------------
__global__ __launch_bounds__(BLOCK) void scatter_kernel(
    const float* __restrict__ coords, const int* __restrict__ types,
    const int* __restrict__ scanOut, const int* __restrict__ offs, int N,
    int B, float* __restrict__ out) {
  __shared__ int wtot[NTYPES][4];   // per-wave inclusive totals
  __shared__ int shBase[NTYPES];    // offs[t] + scanOut[t*B+b]

  const int tid = threadIdx.x;
  const int b = blockIdx.x;
  const int lane = tid & 63;
  const int wave = tid >> 6;
  const int run = b * CHUNK + tid * ITEMS;
  const bool active = (run < N);

  int ty[ITEMS];
  int cnt[NTYPES];
#pragma unroll
  for (int t = 0; t < NTYPES; ++t) cnt[t] = 0;
#pragma unroll
  for (int k = 0; k < ITEMS; ++k) ty[k] = -1;

  float c[ITEMS * 3];
  if (active) {
    const int4* p = (const int4*)(types + run);
    int4 a0 = p[0], a1 = p[1];
    int tt[ITEMS] = {a0.x, a0.y, a0.z, a0.w, a1.x, a1.y, a1.z, a1.w};
#pragma unroll
    for (int k = 0; k < ITEMS; ++k) ty[k] = tt[k];
    const float4* cp = (const float4*)(coords + (size_t)run * 3);
#pragma unroll
    for (int q = 0; q < (ITEMS * 3) / 4; ++q) {
      float4 v = cp[q];
      c[4 * q + 0] = v.x;
      c[4 * q + 1] = v.y;
      c[4 * q + 2] = v.z;
      c[4 * q + 3] = v.w;
    }
#pragma unroll
    for (int k = 0; k < ITEMS; ++k) {
#pragma unroll
      for (int t = 0; t < NTYPES; ++t) cnt[t] += (ty[k] == t) ? 1 : 0;
    }
  }

  // Wave-level stable exclusive scan, 2 types packed per u32
  // (wave-inclusive sums <= 512 < 2^16, no field overflow).
  int pk[6];
#pragma unroll
  for (int q = 0; q < 5; ++q) pk[q] = cnt[2 * q] | (cnt[2 * q + 1] << 16);
  pk[5] = cnt[10];
#pragma unroll
  for (int o = 1; o < 64; o <<= 1) {
    int v0 = __shfl_up(pk[0], o);
    int v1 = __shfl_up(pk[1], o);
    int v2 = __shfl_up(pk[2], o);
    int v3 = __shfl_up(pk[3], o);
    int v4 = __shfl_up(pk[4], o);
    int v5 = __shfl_up(pk[5], o);
    if (lane >= o) {
      pk[0] += v0;
      pk[1] += v1;
      pk[2] += v2;
      pk[3] += v3;
      pk[4] += v4;
      pk[5] += v5;
    }
  }
  int rank[NTYPES];  // starts as lane-exclusive rank; becomes global slot
#pragma unroll
  for (int t = 0; t < NTYPES; ++t) {
    const int incl = (pk[t >> 1] >> ((t & 1) * 16)) & 0xFFFF;
    if (lane == 63) wtot[t][wave] = incl;
    rank[t] = incl - cnt[t];
  }
  // Per-block global segment bases (independent of wtot -> same barrier).
  if (tid < NTYPES) shBase[tid] = offs[tid] + scanOut[tid * B + b];
  __syncthreads();

  // Finalize: global slot = segment base + wave base + lane-exclusive rank.
#pragma unroll
  for (int t = 0; t < NTYPES; ++t) {
    int wb = 0;
#pragma unroll
    for (int w = 0; w < 3; ++w) wb += (w < wave) ? wtot[t][w] : 0;
    rank[t] += wb + shBase[t];
  }

  // Direct stable scatter to global.
  if (active) {
#pragma unroll
    for (int k = 0; k < ITEMS; ++k) {
      const int t0 = ty[k];
      int slot = 0;
#pragma unroll
      for (int t = 0; t < NTYPES; ++t) {
        if (t0 == t) {
          slot = rank[t];
          rank[t] += 1;
        }
      }
      const int dst = 3 * slot;
      out[dst + 0] = c[3 * k + 0];
      out[dst + 1] = c[3 * k + 1];
      out[dst + 2] = c[3 * k + 2];
    }
  }
}

extern "C" void kernel_launch(void* const* d_in, const int* in_sizes, int n_in,
                              void* d_out, int out_size, void* d_ws,
                              size_t ws_size, hipStream_t stream) {
  const float* coords = (const float*)d_in[0];
  const int* types = (const int*)d_in[1];
  const int N = in_sizes[1];              // 4,000,000 atoms
  const int B = (N + CHUNK - 1) / CHUNK;  // 1954 blocks

  int* bc = (int*)d_ws;              // [NTYPES * B]
  int* scanOut = bc + NTYPES * B;    // [NTYPES * B]
  int* offs = scanOut + NTYPES * B;  // [NTYPES]
  float* out = (float*)d_out;
  float* outTail = out + (size_t)3 * N;  // counts then offsets, as floats

  hist_kernel<<<B, BLOCK, 0, stream>>>(types, N, B, bc);
  scan_kernel<<<1, NTYPES * 64, 0, stream>>>(bc, B, scanOut, offs, outTail);
  scatter_kernel<<<B, BLOCK, 0, stream>>>(coords, types, scanOut, offs, N, B,
                                          out);
}

// Round 7
// 138.939 us; speedup vs baseline: 1.0661x; 1.0661x over previous
//
#include <hip/hip_runtime.h>

#define NTYPES 11
#define BLOCK  256               // hist block size (unchanged from r0)
#define ITEMS  8                 // hist items/thread (unchanged from r0)
#define CHUNK  (BLOCK * ITEMS)   // 2048 atoms per block (shared by all kernels)
#define MAXCH  32                // max scan chunks (B <= 2048)
#define SBLOCK 512               // scatter block size (8 waves)
#define SITEMS 4                 // scatter items/thread (SBLOCK*SITEMS == CHUNK)

// ---------------------------------------------------------------------------
// Kernel 1: per-block per-type histogram.  (byte-identical to r0 baseline)
// bc[t*B + b] = number of atoms of type t in block b's chunk.
// ---------------------------------------------------------------------------
__global__ __launch_bounds__(BLOCK) void hist_kernel(
    const int* __restrict__ types, int N, int B, int* __restrict__ bc) {
  __shared__ int shCnt[NTYPES];
  const int tid = threadIdx.x;
  const int b = blockIdx.x;
  if (tid < NTYPES) shCnt[tid] = 0;
  __syncthreads();

  const int run = b * CHUNK + tid * ITEMS;
  int cnt[NTYPES];
#pragma unroll
  for (int t = 0; t < NTYPES; ++t) cnt[t] = 0;

  if (run < N) {
    const int4* p = (const int4*)(types + run);
    int4 a0 = p[0], a1 = p[1];
    int ty[ITEMS] = {a0.x, a0.y, a0.z, a0.w, a1.x, a1.y, a1.z, a1.w};
#pragma unroll
    for (int k = 0; k < ITEMS; ++k) {
#pragma unroll
      for (int t = 0; t < NTYPES; ++t) cnt[t] += (ty[k] == t) ? 1 : 0;
    }
  }

  const int lane = tid & 63;
#pragma unroll
  for (int t = 0; t < NTYPES; ++t) {
    int v = cnt[t];
    for (int o = 32; o >= 1; o >>= 1) v += __shfl_down(v, o);
    if (lane == 0) atomicAdd(&shCnt[t], v);
  }
  __syncthreads();
  if (tid < NTYPES) bc[tid * B + b] = shCnt[tid];
}

// ---------------------------------------------------------------------------
// Kernel 2: one block, 11 waves; wave t scans type t's block-counts.
// (byte-identical to r0 baseline)
// ---------------------------------------------------------------------------
__global__ __launch_bounds__(NTYPES * 64) void scan_kernel(
    const int* __restrict__ bc, int B, int* __restrict__ scanOut,
    int* __restrict__ offs, float* __restrict__ outTail) {
  __shared__ int totals[NTYPES];
  const int lane = threadIdx.x & 63;
  const int t = threadIdx.x >> 6;
  const int nch = (B + 63) >> 6;

  int x[MAXCH];
#pragma unroll
  for (int c = 0; c < MAXCH; ++c) {
    const int idx = c * 64 + lane;
    x[c] = (c < nch && idx < B) ? bc[t * B + idx] : 0;
  }

  int carry = 0;
#pragma unroll
  for (int c = 0; c < MAXCH; ++c) {
    if (c >= nch) break;
    int incl = x[c];
#pragma unroll
    for (int o = 1; o < 64; o <<= 1) {
      int v = __shfl_up(incl, o);
      if (lane >= o) incl += v;
    }
    incl += carry;
    const int idx = c * 64 + lane;
    if (idx < B) scanOut[t * B + idx] = incl - x[c];
    carry = __shfl(incl, 63);
  }
  if (lane == 0) totals[t] = carry;
  __syncthreads();

  if (threadIdx.x == 0) {
    int off = 0;
    for (int u = 0; u < NTYPES; ++u) {
      const int c = totals[u];
      offs[u] = off;
      outTail[u] = (float)c;            // counts (as float values)
      outTail[NTYPES + u] = (float)off; // offsets (as float values)
      off += c;
    }
  }
}

// ---------------------------------------------------------------------------
// Kernel 3: stable scatter with LDS bucket staging (r0 structure).
// ONLY change vs r0: 512 threads x 4 items (same 2048-atom chunk, same 24 KB
// LDS) -> 8 waves/block, 4 blocks/CU = 32 waves/CU (was 6 blocks x 4 waves
// = 24). Halved per-thread arrays keep VGPR <= 64 for the full occupancy.
// More co-resident waves -> better overlap of other blocks' HBM phases with
// this block's barrier-separated compute phases.
// ---------------------------------------------------------------------------
__global__ __launch_bounds__(SBLOCK) void scatter_kernel(
    const float* __restrict__ coords, const int* __restrict__ types,
    const int* __restrict__ scanOut, const int* __restrict__ offs, int N,
    int B, float* __restrict__ out) {
  __shared__ float shC[CHUNK * 3];      // 24 KB type-sorted coords
  __shared__ int wtot[NTYPES][8];       // per-wave inclusive totals
  __shared__ int shOff[NTYPES + 1];     // local bucket offsets (exclusive)
  __shared__ int shDelta[NTYPES];       // 3*(globalBase[t] - shOff[t])

  const int tid = threadIdx.x;
  const int b = blockIdx.x;
  const int lane = tid & 63;
  const int wave = tid >> 6;
  const int run = b * CHUNK + tid * SITEMS;
  const bool active = (run < N);

  int ty[SITEMS];
  int cnt[NTYPES];
#pragma unroll
  for (int t = 0; t < NTYPES; ++t) cnt[t] = 0;
#pragma unroll
  for (int k = 0; k < SITEMS; ++k) ty[k] = -1;

  float c[SITEMS * 3];
  if (active) {
    const int4 a0 = *(const int4*)(types + run);
    int tt[SITEMS] = {a0.x, a0.y, a0.z, a0.w};
#pragma unroll
    for (int k = 0; k < SITEMS; ++k) ty[k] = tt[k];
    const float4* cp = (const float4*)(coords + (size_t)run * 3);
#pragma unroll
    for (int q = 0; q < (SITEMS * 3) / 4; ++q) {
      float4 v = cp[q];
      c[4 * q + 0] = v.x;
      c[4 * q + 1] = v.y;
      c[4 * q + 2] = v.z;
      c[4 * q + 3] = v.w;
    }
#pragma unroll
    for (int k = 0; k < SITEMS; ++k) {
#pragma unroll
      for (int t = 0; t < NTYPES; ++t) cnt[t] += (ty[k] == t) ? 1 : 0;
    }
  }

  // Wave-level stable exclusive scan per type (unpacked, as in r0).
  int rank[NTYPES];
#pragma unroll
  for (int t = 0; t < NTYPES; ++t) {
    int incl = cnt[t];
#pragma unroll
    for (int o = 1; o < 64; o <<= 1) {
      int v = __shfl_up(incl, o);
      if (lane >= o) incl += v;
    }
    if (lane == 63) wtot[t][wave] = incl;
    rank[t] = incl - cnt[t];  // exclusive within wave
  }
  __syncthreads();

  // Local bucket offsets + global deltas (threads 0..NTYPES-1).
  if (tid < NTYPES) {
    int loc = 0;
    for (int u = 0; u < tid; ++u) {
      int s = 0;
#pragma unroll
      for (int w = 0; w < 8; ++w) s += wtot[u][w];
      loc += s;
    }
    shOff[tid] = loc;
    shDelta[tid] = 3 * (offs[tid] + scanOut[tid * B + b] - loc);
    if (tid == NTYPES - 1) {
      int s = 0;
#pragma unroll
      for (int w = 0; w < 8; ++w) s += wtot[tid][w];
      shOff[NTYPES] = loc + s;
    }
  }
  __syncthreads();

  // Finalize local ranks: bucket base + wave base + lane-exclusive.
#pragma unroll
  for (int t = 0; t < NTYPES; ++t) {
    int wb = 0;
#pragma unroll
    for (int w = 0; w < 7; ++w) wb += (w < wave) ? wtot[t][w] : 0;
    rank[t] += wb + shOff[t];
  }

  // Scatter coords into type-sorted LDS buffer.
  if (active) {
#pragma unroll
    for (int k = 0; k < SITEMS; ++k) {
      const int t0 = ty[k];
      int slot = 0;
#pragma unroll
      for (int t = 0; t < NTYPES; ++t) {
        if (t0 == t) {
          slot = rank[t];
          rank[t] += 1;
        }
      }
      shC[3 * slot + 0] = c[3 * k + 0];
      shC[3 * slot + 1] = c[3 * k + 1];
      shC[3 * slot + 2] = c[3 * k + 2];
    }
  }
  __syncthreads();

  // Coalesced copy-out: slot s -> global float index 3*s + delta3[type(s)].
  const int total = shOff[NTYPES];
  int offr[NTYPES];
  int dlt[NTYPES];
#pragma unroll
  for (int t = 0; t < NTYPES; ++t) {
    offr[t] = shOff[t];
    dlt[t] = shDelta[t];
  }
#pragma unroll
  for (int k = 0; k < SITEMS; ++k) {
    const int s = k * SBLOCK + tid;
    if (s < total) {
      int d = dlt[0];
#pragma unroll
      for (int t = 1; t < NTYPES; ++t) d = (s >= offr[t]) ? dlt[t] : d;
      const int src = 3 * s;
      out[src + d + 0] = shC[src + 0];
      out[src + d + 1] = shC[src + 1];
      out[src + d + 2] = shC[src + 2];
    }
  }
}

extern "C" void kernel_launch(void* const* d_in, const int* in_sizes, int n_in,
                              void* d_out, int out_size, void* d_ws,
                              size_t ws_size, hipStream_t stream) {
  const float* coords = (const float*)d_in[0];
  const int* types = (const int*)d_in[1];
  const int N = in_sizes[1];              // 4,000,000 atoms
  const int B = (N + CHUNK - 1) / CHUNK;  // 1954 blocks

  int* bc = (int*)d_ws;              // [NTYPES * B]
  int* scanOut = bc + NTYPES * B;    // [NTYPES * B]
  int* offs = scanOut + NTYPES * B;  // [NTYPES]
  float* out = (float*)d_out;
  float* outTail = out + (size_t)3 * N;  // counts then offsets, as floats

  hist_kernel<<<B, BLOCK, 0, stream>>>(types, N, B, bc);
  scan_kernel<<<1, NTYPES * 64, 0, stream>>>(bc, B, scanOut, offs, outTail);
  scatter_kernel<<<B, SBLOCK, 0, stream>>>(coords, types, scanOut, offs, N, B,
                                           out);
}

// Round 8
// 137.300 us; speedup vs baseline: 1.0788x; 1.0119x over previous
//
#include <hip/hip_runtime.h>

#define NTYPES 11
#define BLOCK  256
#define ITEMS  8
#define CHUNK  (BLOCK * ITEMS)   // 2048 atoms per block
#define MAXCH  32                // max scan chunks (B <= 2048)

// ---------------------------------------------------------------------------
// Kernel 1: per-block per-type histogram + 4-bit type packing.
// bc[t*B + b] = count of type t in block b's chunk.
// packed[b*BLOCK + tid] = 8 types as nibbles (types < 16). Scatter reads the
// 2 MB packed array instead of re-reading the 16 MB types array.
// ---------------------------------------------------------------------------
__global__ __launch_bounds__(BLOCK) void hist_kernel(
    const int* __restrict__ types, int N, int B, int* __restrict__ bc,
    unsigned int* __restrict__ packed) {
  __shared__ int shCnt[NTYPES];
  const int tid = threadIdx.x;
  const int b = blockIdx.x;
  if (tid < NTYPES) shCnt[tid] = 0;
  __syncthreads();

  const int run = b * CHUNK + tid * ITEMS;
  int cnt[NTYPES];
#pragma unroll
  for (int t = 0; t < NTYPES; ++t) cnt[t] = 0;

  if (run < N) {
    const int4* p = (const int4*)(types + run);
    int4 a0 = p[0], a1 = p[1];
    int ty[ITEMS] = {a0.x, a0.y, a0.z, a0.w, a1.x, a1.y, a1.z, a1.w};
    unsigned int pk = 0;
#pragma unroll
    for (int k = 0; k < ITEMS; ++k) pk |= ((unsigned int)ty[k]) << (4 * k);
    packed[b * BLOCK + tid] = pk;
#pragma unroll
    for (int k = 0; k < ITEMS; ++k) {
#pragma unroll
      for (int t = 0; t < NTYPES; ++t) cnt[t] += (ty[k] == t) ? 1 : 0;
    }
  }

  const int lane = tid & 63;
#pragma unroll
  for (int t = 0; t < NTYPES; ++t) {
    int v = cnt[t];
    for (int o = 32; o >= 1; o >>= 1) v += __shfl_down(v, o);
    if (lane == 0) atomicAdd(&shCnt[t], v);
  }
  __syncthreads();
  if (tid < NTYPES) bc[tid * B + b] = shCnt[tid];
}

// ---------------------------------------------------------------------------
// Kernel 2: one block, 11 waves; wave t scans type t's block-counts.
// (byte-identical to r0 baseline)
// ---------------------------------------------------------------------------
__global__ __launch_bounds__(NTYPES * 64) void scan_kernel(
    const int* __restrict__ bc, int B, int* __restrict__ scanOut,
    int* __restrict__ offs, float* __restrict__ outTail) {
  __shared__ int totals[NTYPES];
  const int lane = threadIdx.x & 63;
  const int t = threadIdx.x >> 6;
  const int nch = (B + 63) >> 6;

  int x[MAXCH];
#pragma unroll
  for (int c = 0; c < MAXCH; ++c) {
    const int idx = c * 64 + lane;
    x[c] = (c < nch && idx < B) ? bc[t * B + idx] : 0;
  }

  int carry = 0;
#pragma unroll
  for (int c = 0; c < MAXCH; ++c) {
    if (c >= nch) break;
    int incl = x[c];
#pragma unroll
    for (int o = 1; o < 64; o <<= 1) {
      int v = __shfl_up(incl, o);
      if (lane >= o) incl += v;
    }
    incl += carry;
    const int idx = c * 64 + lane;
    if (idx < B) scanOut[t * B + idx] = incl - x[c];
    carry = __shfl(incl, 63);
  }
  if (lane == 0) totals[t] = carry;
  __syncthreads();

  if (threadIdx.x == 0) {
    int off = 0;
    for (int u = 0; u < NTYPES; ++u) {
      const int c = totals[u];
      offs[u] = off;
      outTail[u] = (float)c;            // counts (as float values)
      outTail[NTYPES + u] = (float)off; // offsets (as float values)
      off += c;
    }
  }
}

// ---------------------------------------------------------------------------
// Kernel 3: stable scatter, r0 structure (grid=B, 256 thr, 24 KB LDS).
// Changes vs r0 (both phase-internal, sync structure untouched):
//  - reads 4-bit packed types (1 dword/thread) instead of 32 B of raw types
//  - copy-out: ds_read_b128 (float4) + one segment-search per 4-float
//    window, per-element fallback only at type-boundary windows (<=10/block).
//    Stores remain scalar dwords (d is only 4 B-aligned).
// ---------------------------------------------------------------------------
__global__ __launch_bounds__(BLOCK) void scatter_kernel(
    const float* __restrict__ coords, const unsigned int* __restrict__ packed,
    const int* __restrict__ scanOut, const int* __restrict__ offs, int N,
    int B, float* __restrict__ out) {
  __shared__ float shC[CHUNK * 3];      // 24 KB type-sorted coords
  __shared__ int wtot[NTYPES][4];       // per-wave inclusive totals
  __shared__ int shOff[NTYPES + 1];     // local bucket offsets (exclusive)
  __shared__ int shDelta[NTYPES];       // 3*(globalBase[t] - shOff[t])

  const int tid = threadIdx.x;
  const int b = blockIdx.x;
  const int lane = tid & 63;
  const int wave = tid >> 6;
  const int run = b * CHUNK + tid * ITEMS;
  const bool active = (run < N);

  int ty[ITEMS];
  int cnt[NTYPES];
#pragma unroll
  for (int t = 0; t < NTYPES; ++t) cnt[t] = 0;
#pragma unroll
  for (int k = 0; k < ITEMS; ++k) ty[k] = -1;

  float c[ITEMS * 3];
  if (active) {
    const unsigned int pk = packed[b * BLOCK + tid];
#pragma unroll
    for (int k = 0; k < ITEMS; ++k) ty[k] = (int)((pk >> (4 * k)) & 0xFu);
    const float4* cp = (const float4*)(coords + (size_t)run * 3);
#pragma unroll
    for (int q = 0; q < (ITEMS * 3) / 4; ++q) {
      float4 v = cp[q];
      c[4 * q + 0] = v.x;
      c[4 * q + 1] = v.y;
      c[4 * q + 2] = v.z;
      c[4 * q + 3] = v.w;
    }
#pragma unroll
    for (int k = 0; k < ITEMS; ++k) {
#pragma unroll
      for (int t = 0; t < NTYPES; ++t) cnt[t] += (ty[k] == t) ? 1 : 0;
    }
  }

  // Wave-level stable exclusive scan per type (unpacked, as in r0).
  int rank[NTYPES];
#pragma unroll
  for (int t = 0; t < NTYPES; ++t) {
    int incl = cnt[t];
#pragma unroll
    for (int o = 1; o < 64; o <<= 1) {
      int v = __shfl_up(incl, o);
      if (lane >= o) incl += v;
    }
    if (lane == 63) wtot[t][wave] = incl;
    rank[t] = incl - cnt[t];  // exclusive within wave
  }
  __syncthreads();

  // Local bucket offsets + global deltas (threads 0..NTYPES-1).
  if (tid < NTYPES) {
    int loc = 0;
    for (int u = 0; u < tid; ++u)
      loc += wtot[u][0] + wtot[u][1] + wtot[u][2] + wtot[u][3];
    shOff[tid] = loc;
    shDelta[tid] = 3 * (offs[tid] + scanOut[tid * B + b] - loc);
    if (tid == NTYPES - 1) {
      shOff[NTYPES] =
          loc + wtot[tid][0] + wtot[tid][1] + wtot[tid][2] + wtot[tid][3];
    }
  }
  __syncthreads();

  // Finalize local ranks: bucket base + wave base + lane-exclusive.
#pragma unroll
  for (int t = 0; t < NTYPES; ++t) {
    int wb = 0;
#pragma unroll
    for (int w = 0; w < 3; ++w) wb += (w < wave) ? wtot[t][w] : 0;
    rank[t] += wb + shOff[t];
  }

  // Scatter coords into type-sorted LDS buffer.
  if (active) {
#pragma unroll
    for (int k = 0; k < ITEMS; ++k) {
      const int t0 = ty[k];
      int slot = 0;
#pragma unroll
      for (int t = 0; t < NTYPES; ++t) {
        if (t0 == t) {
          slot = rank[t];
          rank[t] += 1;
        }
      }
      shC[3 * slot + 0] = c[3 * k + 0];
      shC[3 * slot + 1] = c[3 * k + 1];
      shC[3 * slot + 2] = c[3 * k + 2];
    }
  }
  __syncthreads();

  // Copy-out over 4-float windows. total3 is a multiple of 4 (3*total,
  // total = 2048 or 256), so windows never straddle total3. A window with
  // d0 == d3 (the common case) lies in one type segment.
  const int total3 = 3 * shOff[NTYPES];
  int offr3[NTYPES];
  int dlt[NTYPES];
#pragma unroll
  for (int t = 0; t < NTYPES; ++t) {
    offr3[t] = 3 * shOff[t];
    dlt[t] = shDelta[t];
  }
  const float4* shC4 = (const float4*)shC;
#pragma unroll
  for (int k = 0; k < (ITEMS * 3) / 4; ++k) {
    const int w = k * BLOCK + tid;
    const int j0 = 4 * w;
    if (j0 < total3) {
      const float4 v = shC4[w];
      int d0 = dlt[0], d3 = dlt[0];
#pragma unroll
      for (int t = 1; t < NTYPES; ++t) {
        d0 = (j0 >= offr3[t]) ? dlt[t] : d0;
        d3 = (j0 + 3 >= offr3[t]) ? dlt[t] : d3;
      }
      if (d0 == d3) {
        out[j0 + d0 + 0] = v.x;
        out[j0 + d0 + 1] = v.y;
        out[j0 + d0 + 2] = v.z;
        out[j0 + d0 + 3] = v.w;
      } else {  // rare: window crosses a type boundary (<=10 windows/block)
        int d1 = dlt[0], d2 = dlt[0];
#pragma unroll
        for (int t = 1; t < NTYPES; ++t) {
          d1 = (j0 + 1 >= offr3[t]) ? dlt[t] : d1;
          d2 = (j0 + 2 >= offr3[t]) ? dlt[t] : d2;
        }
        out[j0 + d0 + 0] = v.x;
        out[j0 + d1 + 1] = v.y;
        out[j0 + d2 + 2] = v.z;
        out[j0 + d3 + 3] = v.w;
      }
    }
  }
}

extern "C" void kernel_launch(void* const* d_in, const int* in_sizes, int n_in,
                              void* d_out, int out_size, void* d_ws,
                              size_t ws_size, hipStream_t stream) {
  const float* coords = (const float*)d_in[0];
  const int* types = (const int*)d_in[1];
  const int N = in_sizes[1];              // 4,000,000 atoms
  const int B = (N + CHUNK - 1) / CHUNK;  // 1954 blocks

  int* bc = (int*)d_ws;                        // [NTYPES * B]
  int* scanOut = bc + NTYPES * B;              // [NTYPES * B]
  int* offs = scanOut + NTYPES * B;            // [NTYPES]
  unsigned int* packed = (unsigned int*)(offs + NTYPES + 1);  // [B * BLOCK]
  float* out = (float*)d_out;
  float* outTail = out + (size_t)3 * N;  // counts then offsets, as floats

  hist_kernel<<<B, BLOCK, 0, stream>>>(types, N, B, bc, packed);
  scan_kernel<<<1, NTYPES * 64, 0, stream>>>(bc, B, scanOut, offs, outTail);
  scatter_kernel<<<B, BLOCK, 0, stream>>>(coords, packed, scanOut, offs, N, B,
                                          out);
}